// Round 8
// baseline (467.500 us; speedup 1.0000x reference)
//
#include <hip/hip_runtime.h>
#include <hip/hip_bf16.h>
#include <math.h>

#define Hdim 512
#define Bdim 32
#define Sdim 2048
#define Kdim 1024            // 2*H
#define Mtot (Bdim * Sdim)   // 65536 rows

// scores GEMM: block = 512 thr = 8 waves; tile 64 rows x 512 cols;
// wave w owns cols [64w, 64w+64). BK=128 (16 chunks of 8 bf16 per 256 B row).
#define BM 64
#define BK 128

typedef __attribute__((ext_vector_type(8))) short short8;
typedef __attribute__((ext_vector_type(4))) float floatx4;

// ---------------- fp32 -> bf16 (RNE) ----------------------------------------
__device__ __forceinline__ short f2bf(float f) {
    union { float f; unsigned u; } v; v.f = f;
    unsigned r = v.u + 0x7fffu + ((v.u >> 16) & 1u);
    return (short)(r >> 16);
}

// 8 fp32 -> 8 bf16 via packed converts
__device__ __forceinline__ short8 cvt8(float4 a, float4 b) {
    union { short8 s; __hip_bfloat162 h[4]; } u;
    u.h[0] = __float22bfloat162_rn(make_float2(a.x, a.y));
    u.h[1] = __float22bfloat162_rn(make_float2(a.z, a.w));
    u.h[2] = __float22bfloat162_rn(make_float2(b.x, b.y));
    u.h[3] = __float22bfloat162_rn(make_float2(b.z, b.w));
    return u.s;
}

__device__ __forceinline__ float fast_tanh(float x) {
    float ax = fabsf(x);
    float e  = __expf(-2.0f * ax);
    float r  = (1.0f - e) * __builtin_amdgcn_rcpf(1.0f + e);
    return copysignf(r, x);
}

// ---------------- Kernel 0: prep = conv_W (blocks 0..511) + dec_proj --------
__global__ __launch_bounds__(256) void prep_kernel(
    const float* __restrict__ W_attn, const float* __restrict__ dec,
    const float* __restrict__ b_attn, short* __restrict__ Wb,
    float* __restrict__ dec_proj)
{
    const int t = threadIdx.x;
    if (blockIdx.x < 512) {
        // W_e fp32 [k][n] -> bf16 [n][k] transpose
        const float* We = W_attn + Hdim * Hdim;   // [1024][512]
        __shared__ short tile[32][33];
        const int k0 = (blockIdx.x >> 4) * 32;
        const int n0 = (blockIdx.x & 15) * 32;
        const int r = t >> 5, c = t & 31;
        #pragma unroll
        for (int rr = 0; rr < 4; ++rr)
            tile[r + rr * 8][c] = f2bf(We[(size_t)(k0 + r + rr * 8) * Hdim + n0 + c]);
        __syncthreads();
        #pragma unroll
        for (int rr = 0; rr < 4; ++rr)
            Wb[(size_t)(n0 + r + rr * 8) * Kdim + k0 + c] = tile[c][r + rr * 8];
    } else {
        // dec_proj = decoder_hide @ W_h + b_attn
        __shared__ float partl[2][128];
        const int bid = blockIdx.x - 512;      // 0..127
        const int b  = bid >> 2;
        const int cb = bid & 3;
        const int c  = cb * 128 + (t & 127);
        const int kh = t >> 7;
        float acc = 0.0f;
        const int kbeg = kh * 256, kend = kbeg + 256;
        #pragma unroll 8
        for (int k = kbeg; k < kend; ++k)
            acc = fmaf(dec[b * Hdim + k], W_attn[(size_t)k * Hdim + c], acc);
        partl[kh][t & 127] = acc;
        __syncthreads();
        if (t < 128)
            dec_proj[b * Hdim + cb * 128 + t] = partl[0][t] + partl[1][t] + b_attn[cb * 128 + t];
    }
}

// ---------------- Kernel 1: fused MFMA scores -------------------------------
// A (enc) fp32->bf16 into double-buffered LDS; BK=128 -> 8 barriers total.
// A global loads prefetched DISTANCE 2 and issued as the LAST loads of each
// iter (after all B issues) so no in-order vmcnt wait retires them early.
// B (Wb bf16, 1 MB, L2-resident) global->reg just-in-time per k-phase.
// LDS chunk swizzle p = q ^ (row&7) with writer chunks {sq, sq+8}:
// conflict-free writes AND reads (bank arithmetic in R8 notes).
__global__ __launch_bounds__(512, 4) void scores_kernel(
    const float* __restrict__ enc,      // [65536][1024] fp32
    const short* __restrict__ Wb,       // [512][1024] bf16 (n-major)
    const float* __restrict__ dec_proj, // [32][512]
    const float* __restrict__ v_w,      // [512]
    float* __restrict__ scores)         // [65536]
{
    __shared__ __align__(16) short Asm[2 * BM * BK];   // 32 KB double-buffered
    __shared__ float redl[BM][8];                      // 2 KB

    const int t    = threadIdx.x;
    const int row0 = blockIdx.x * BM;
    const int b    = row0 / Sdim;        // uniform per block

    const int w    = t >> 6;             // wave 0..7 -> cols [64w, 64w+64)
    const int lane = t & 63;
    const int ln   = lane & 15;
    const int quad = lane >> 4;

    // ---- A staging: thread (row sm, chunk sq) loads chunks sq and sq+8 ----
    const int sm = t >> 3;               // 0..63
    const int sq = t & 7;                // 0..7
    const float* Ag = enc + (size_t)(row0 + sm) * Kdim + sq * 8;
    const int awo0 = sm * BK + ((sq       ^ (sm & 7)) * 8);
    const int awo1 = sm * BK + (((sq + 8) ^ (sm & 7)) * 8);

    // ---- A frag read addresses ----
    int arow[4];
    #pragma unroll
    for (int i = 0; i < 4; ++i) arow[i] = (i * 16 + ln) * BK;

    // ---- B per-lane global base: row (w*64 + ln), k-offset quad*8 ----
    const short* Bl = Wb + (size_t)(w * 64 + ln) * Kdim + quad * 8;

    floatx4 acc[4][4];
    #pragma unroll
    for (int i = 0; i < 4; ++i)
        #pragma unroll
        for (int j = 0; j < 4; ++j)
            acc[i][j] = (floatx4)(0.0f);

    // ---- prologue: prefetch A tiles 0 and 1 (distance 2) ----
    float4 ra[2][4];
    {
        const float4* g0 = (const float4*)Ag;            // tile 0, chunks sq / sq+8
        ra[0][0] = g0[0]; ra[0][1] = g0[1];
        const float4* g0b = (const float4*)(Ag + 64);
        ra[0][2] = g0b[0]; ra[0][3] = g0b[1];
        const float4* g1 = (const float4*)(Ag + BK);     // tile 1
        ra[1][0] = g1[0]; ra[1][1] = g1[1];
        const float4* g1b = (const float4*)(Ag + BK + 64);
        ra[1][2] = g1b[0]; ra[1][3] = g1b[1];
    }

    for (int i = 0; i < 8; ++i) {
        const int kt = i << 7;
        short* Ab = Asm + (i & 1) * (BM * BK);
        // stage A from prefetched regs (waits only on this tile's A loads)
        *(short8*)&Ab[awo0] = cvt8(ra[i & 1][0], ra[i & 1][1]);
        *(short8*)&Ab[awo1] = cvt8(ra[i & 1][2], ra[i & 1][3]);
        __syncthreads();                 // nothing else outstanding -> cheap

        // ---- 4 k-phases of 32 k each ----
        #pragma unroll
        for (int p = 0; p < 4; ++p) {
            // B just-in-time (L2 hits)
            short8 bfr[4];
            #pragma unroll
            for (int j = 0; j < 4; ++j)
                bfr[j] = *(const short8*)(Bl + (size_t)j * 16 * Kdim + kt + p * 32);

            // A prefetch for tile i+2: LAST loads of this iter (after all B)
            if (p == 3 && i < 6) {
                const float4* g  = (const float4*)(Ag + kt + 2 * BK);
                ra[i & 1][0] = g[0]; ra[i & 1][1] = g[1];
                const float4* gb = (const float4*)(Ag + kt + 2 * BK + 64);
                ra[i & 1][2] = gb[0]; ra[i & 1][3] = gb[1];
            }

            const int pf = ((p * 4 + quad) ^ (ln & 7)) * 8;
            short8 af[4];
            #pragma unroll
            for (int i2 = 0; i2 < 4; ++i2)
                af[i2] = *(const short8*)&Ab[arow[i2] + pf];
            #pragma unroll
            for (int i2 = 0; i2 < 4; ++i2)
                #pragma unroll
                for (int j = 0; j < 4; ++j)
                    acc[i2][j] = __builtin_amdgcn_mfma_f32_16x16x32_bf16(
                                     af[i2], bfr[j], acc[i2][j], 0, 0, 0);
        }
    }

    // ---- epilogue: +dec_proj, tanh, *v_w; wave sums its 64 cols ----
    float dpv[4], vwv[4];
    #pragma unroll
    for (int j = 0; j < 4; ++j) {
        int col = w * 64 + j * 16 + ln;
        dpv[j] = dec_proj[b * Hdim + col];
        vwv[j] = v_w[col];
    }
    #pragma unroll
    for (int i = 0; i < 4; ++i) {
        #pragma unroll
        for (int reg = 0; reg < 4; ++reg) {
            float s = 0.0f;
            #pragma unroll
            for (int j = 0; j < 4; ++j) {
                float x = acc[i][j][reg] + dpv[j];
                s = fmaf(vwv[j], fast_tanh(x), s);
            }
            s += __shfl_xor(s, 1, 64);
            s += __shfl_xor(s, 2, 64);
            s += __shfl_xor(s, 4, 64);
            s += __shfl_xor(s, 8, 64);
            if (ln == 0)
                redl[i * 16 + quad * 4 + reg][w] = s;
        }
    }
    __syncthreads();
    if (t < BM) {
        float s = 0.0f;
        #pragma unroll
        for (int wv = 0; wv < 8; ++wv) s += redl[t][wv];
        scores[row0 + t] = s;
    }
}

// ---------------- Kernel 2: masked softmax over S per batch -----------------
__global__ __launch_bounds__(256) void softmax_kernel(
    const float* __restrict__ scores, const int* __restrict__ mask,
    float* __restrict__ out)
{
    __shared__ float sred[8];
    const int b = blockIdx.x;
    const int t = threadIdx.x;
    const int lane = t & 63;
    const int wid  = t >> 6;

    float x[8];
    float m = -1e30f;
    #pragma unroll
    for (int j = 0; j < 8; ++j) {
        int idx = b * Sdim + j * 256 + t;
        float v = scores[idx];
        if (mask[idx] == 0) v = -100000.0f;
        x[j] = v;
        m = fmaxf(m, v);
    }
    #pragma unroll
    for (int off = 32; off >= 1; off >>= 1)
        m = fmaxf(m, __shfl_xor(m, off, 64));
    if (lane == 0) sred[wid] = m;
    __syncthreads();
    m = fmaxf(fmaxf(sred[0], sred[1]), fmaxf(sred[2], sred[3]));

    float s = 0.0f;
    #pragma unroll
    for (int j = 0; j < 8; ++j) {
        float e = __expf(x[j] - m);
        x[j] = e;
        s += e;
    }
    #pragma unroll
    for (int off = 32; off >= 1; off >>= 1)
        s += __shfl_xor(s, off, 64);
    if (lane == 0) sred[4 + wid] = s;
    __syncthreads();
    s = sred[4] + sred[5] + sred[6] + sred[7];

    const float inv = 1.0f / s;
    #pragma unroll
    for (int j = 0; j < 8; ++j)
        out[b * Sdim + j * 256 + t] = x[j] * inv;
}

// ---------------- launch ----------------------------------------------------
extern "C" void kernel_launch(void* const* d_in, const int* in_sizes, int n_in,
                              void* d_out, int out_size, void* d_ws, size_t ws_size,
                              hipStream_t stream) {
    const float* dec  = (const float*)d_in[0];   // (B, H)
    const float* enc  = (const float*)d_in[1];   // (B, S, 2H)
    const int*   mask = (const int*)  d_in[2];   // (B, S)
    const float* W    = (const float*)d_in[3];   // (3H, H)
    const float* ba   = (const float*)d_in[4];   // (H,)
    const float* vw   = (const float*)d_in[5];   // (H,)
    float* out = (float*)d_out;                  // (B, S)

    // workspace layout (~1.3 MB)
    float* dec_proj = (float*)d_ws;                       // 32*512 f   = 64 KB
    short* Wb       = (short*)(dec_proj + Bdim * Hdim);   // 512*1024 s = 1 MB
    float* scores   = (float*)(Wb + Hdim * Kdim);         // 65536 f    = 256 KB

    prep_kernel<<<640, 256, 0, stream>>>(W, dec, ba, Wb, dec_proj);
    scores_kernel<<<Mtot / BM, 512, 0, stream>>>(enc, Wb, dec_proj, vw, scores);
    softmax_kernel<<<Bdim, 256, 0, stream>>>(scores, mask, out);
}

// Round 9
// 426.731 us; speedup vs baseline: 1.0955x; 1.0955x over previous
//
#include <hip/hip_runtime.h>
#include <hip/hip_bf16.h>
#include <math.h>

#define Hdim 512
#define Bdim 32
#define Sdim 2048
#define Kdim 1024            // 2*H
#define Mtot (Bdim * Sdim)   // 65536 rows

// scores GEMM: block = 512 thr = 8 waves; tile 64 rows x 512 cols;
// wave w owns cols [64w, 64w+64). BK=64. (R7 structure.)
#define BM 64
#define BK 64

typedef __attribute__((ext_vector_type(8))) short short8;
typedef __attribute__((ext_vector_type(4))) float floatx4;

// ---------------- fp32 -> bf16 (RNE) ----------------------------------------
__device__ __forceinline__ short f2bf(float f) {
    union { float f; unsigned u; } v; v.f = f;
    unsigned r = v.u + 0x7fffu + ((v.u >> 16) & 1u);
    return (short)(r >> 16);
}

// 8 fp32 -> 8 bf16 via packed converts
__device__ __forceinline__ short8 cvt8(float4 a, float4 b) {
    union { short8 s; __hip_bfloat162 h[4]; } u;
    u.h[0] = __float22bfloat162_rn(make_float2(a.x, a.y));
    u.h[1] = __float22bfloat162_rn(make_float2(a.z, a.w));
    u.h[2] = __float22bfloat162_rn(make_float2(b.x, b.y));
    u.h[3] = __float22bfloat162_rn(make_float2(b.z, b.w));
    return u.s;
}

__device__ __forceinline__ float fast_tanh(float x) {
    float ax = fabsf(x);
    float e  = __expf(-2.0f * ax);
    float r  = (1.0f - e) * __builtin_amdgcn_rcpf(1.0f + e);
    return copysignf(r, x);
}

// ---------------- Kernel 0: prep --------------------------------------------
// blocks 0..511: W_e fp32 [k][n] -> bf16 PACKED in MFMA-fragment order:
//   short8 index = (nt*32 + ks)*64 + lane,  lane = quad*16 + (n&15),
//   holding B[n = nt*16 + (n&15)][k = ks*32 + quad*8 .. +7].
// -> scores-kernel B loads are lane-contiguous 1 KB (dense lines).
// blocks 512..639: dec_proj = decoder_hide @ W_h + b_attn.
__global__ __launch_bounds__(256) void prep_kernel(
    const float* __restrict__ W_attn, const float* __restrict__ dec,
    const float* __restrict__ b_attn, short* __restrict__ Wbp,
    float* __restrict__ dec_proj)
{
    const int t = threadIdx.x;
    if (blockIdx.x < 512) {
        const float* We = W_attn + Hdim * Hdim;   // [1024][512]
        __shared__ short tile[32][33];            // [k_loc][n_loc]
        const int k0 = (blockIdx.x >> 4) * 32;
        const int n0 = (blockIdx.x & 15) * 32;
        const int r = t >> 5, c = t & 31;
        #pragma unroll
        for (int rr = 0; rr < 4; ++rr)
            tile[r + rr * 8][c] = f2bf(We[(size_t)(k0 + r + rr * 8) * Hdim + n0 + c]);
        __syncthreads();
        if (t < 128) {
            const int n_loc = t >> 2;             // 0..31
            const int q     = t & 3;              // quad = (k>>3)&3
            const int nt    = (n0 + n_loc) >> 4;
            const int lnn   = (n0 + n_loc) & 15;
            const int ks    = k0 >> 5;
            short8 v;
            #pragma unroll
            for (int r2 = 0; r2 < 8; ++r2) v[r2] = tile[q * 8 + r2][n_loc];
            ((short8*)Wbp)[((nt * 32 + ks) * 64) + q * 16 + lnn] = v;
        }
    } else {
        __shared__ float partl[2][128];
        const int bid = blockIdx.x - 512;      // 0..127
        const int b  = bid >> 2;
        const int cb = bid & 3;
        const int c  = cb * 128 + (t & 127);
        const int kh = t >> 7;
        float acc = 0.0f;
        const int kbeg = kh * 256, kend = kbeg + 256;
        #pragma unroll 8
        for (int k = kbeg; k < kend; ++k)
            acc = fmaf(dec[b * Hdim + k], W_attn[(size_t)k * Hdim + c], acc);
        partl[kh][t & 127] = acc;
        __syncthreads();
        if (t < 128)
            dec_proj[b * Hdim + cb * 128 + t] = partl[0][t] + partl[1][t] + b_attn[cb * 128 + t];
    }
}

// ---------------- Kernel 1: fused MFMA scores (R7 + packed B) ---------------
// A (enc) fp32->bf16 into double-buffered LDS, ONE barrier/iter, issue order
// B-loads-then-A-prefetch (in-order vmcnt). B fragments loaded DENSE from the
// packed layout: one 16 B/lane contiguous 1 KB load per (n-tile, k-step).
__global__ __launch_bounds__(512, 4) void scores_kernel(
    const float* __restrict__ enc,      // [65536][1024] fp32
    const short* __restrict__ Wbp,      // packed B fragments (1 MB, L2-resident)
    const float* __restrict__ dec_proj, // [32][512]
    const float* __restrict__ v_w,      // [512]
    float* __restrict__ scores)         // [65536]
{
    __shared__ __align__(16) short Asm[2 * BM * BK];   // 16 KB double-buffered
    __shared__ float redl[BM][8];                      // 2 KB

    const int t    = threadIdx.x;
    const int row0 = blockIdx.x * BM;
    const int b    = row0 / Sdim;        // uniform per block

    const int w    = t >> 6;             // wave 0..7 -> cols [64w, 64w+64)
    const int lane = t & 63;
    const int ln   = lane & 15;
    const int quad = lane >> 4;

    // ---- A staging: thread -> (row sm, 8-float chunk sq), one short8 write
    const int sm = t >> 3;               // 0..63
    const int sq = t & 7;                // 0..7
    const float* Ag = enc + (size_t)(row0 + sm) * Kdim + sq * 8;
    const int awo = sm * BK + ((sq ^ (sm & 7)) * 8);

    // ---- A frag read addresses (R7-verified swizzle family) ----
    int arow[4];
    #pragma unroll
    for (int i = 0; i < 4; ++i) arow[i] = (i * 16 + ln) * BK;
    const int pf0 = (quad       ^ (ln & 7)) * 8;   // phase 0: chunks 0..3
    const int pf1 = ((4 + quad) ^ (ln & 7)) * 8;   // phase 1: chunks 4..7

    // ---- B packed per-lane base ----
    const short8* Bp = ((const short8*)Wbp) + lane;   // + (nt*32 + ks)*64

    floatx4 acc[4][4];
    #pragma unroll
    for (int i = 0; i < 4; ++i)
        #pragma unroll
        for (int j = 0; j < 4; ++j)
            acc[i][j] = (floatx4)(0.0f);

    // ---- prologue: prefetch A tile 0 (32 B/thread) ----
    float4 ra0, ra1;
    {
        const float4* g = (const float4*)Ag;
        ra0 = g[0]; ra1 = g[1];
    }

    for (int kt = 0; kt < Kdim; kt += BK) {
        short* Ab = Asm + ((kt >> 6) & 1) * (BM * BK);
        // stage A from prefetched regs (waits only on A), swizzled write
        *(short8*)&Ab[awo] = cvt8(ra0, ra1);
        __syncthreads();                 // nothing else outstanding -> cheap

        // ---- B loads for BOTH phases first (dense 1 KB each, L2 hits) ----
        const int ks = kt >> 5;
        short8 b0[4], b1[4];
        #pragma unroll
        for (int j = 0; j < 4; ++j)
            b0[j] = Bp[(size_t)((w * 4 + j) * 32 + ks) * 64];
        #pragma unroll
        for (int j = 0; j < 4; ++j)
            b1[j] = Bp[(size_t)((w * 4 + j) * 32 + ks + 1) * 64];

        // ---- A prefetch LAST (HBM; stays in flight through both phases) ----
        if (kt + BK < Kdim) {
            const float4* g = (const float4*)(Ag + kt + BK);
            ra0 = g[0]; ra1 = g[1];
        }

        // ---- phase 0 ----
        short8 af[4];
        #pragma unroll
        for (int i = 0; i < 4; ++i) af[i] = *(const short8*)&Ab[arow[i] + pf0];
        #pragma unroll
        for (int i = 0; i < 4; ++i)
            #pragma unroll
            for (int j = 0; j < 4; ++j)
                acc[i][j] = __builtin_amdgcn_mfma_f32_16x16x32_bf16(
                                af[i], b0[j], acc[i][j], 0, 0, 0);
        // ---- phase 1 ----
        #pragma unroll
        for (int i = 0; i < 4; ++i) af[i] = *(const short8*)&Ab[arow[i] + pf1];
        #pragma unroll
        for (int i = 0; i < 4; ++i)
            #pragma unroll
            for (int j = 0; j < 4; ++j)
                acc[i][j] = __builtin_amdgcn_mfma_f32_16x16x32_bf16(
                                af[i], b1[j], acc[i][j], 0, 0, 0);
    }

    // ---- epilogue: +dec_proj, tanh, *v_w; wave sums its 64 cols ----
    float dpv[4], vwv[4];
    #pragma unroll
    for (int j = 0; j < 4; ++j) {
        int col = w * 64 + j * 16 + ln;
        dpv[j] = dec_proj[b * Hdim + col];
        vwv[j] = v_w[col];
    }
    #pragma unroll
    for (int i = 0; i < 4; ++i) {
        #pragma unroll
        for (int reg = 0; reg < 4; ++reg) {
            float s = 0.0f;
            #pragma unroll
            for (int j = 0; j < 4; ++j) {
                float x = acc[i][j][reg] + dpv[j];
                s = fmaf(vwv[j], fast_tanh(x), s);
            }
            s += __shfl_xor(s, 1, 64);
            s += __shfl_xor(s, 2, 64);
            s += __shfl_xor(s, 4, 64);
            s += __shfl_xor(s, 8, 64);
            if (ln == 0)
                redl[i * 16 + quad * 4 + reg][w] = s;
        }
    }
    __syncthreads();
    if (t < BM) {
        float s = 0.0f;
        #pragma unroll
        for (int wv = 0; wv < 8; ++wv) s += redl[t][wv];
        scores[row0 + t] = s;
    }
}

// ---------------- Kernel 2: masked softmax over S per batch -----------------
__global__ __launch_bounds__(256) void softmax_kernel(
    const float* __restrict__ scores, const int* __restrict__ mask,
    float* __restrict__ out)
{
    __shared__ float sred[8];
    const int b = blockIdx.x;
    const int t = threadIdx.x;
    const int lane = t & 63;
    const int wid  = t >> 6;

    float x[8];
    float m = -1e30f;
    #pragma unroll
    for (int j = 0; j < 8; ++j) {
        int idx = b * Sdim + j * 256 + t;
        float v = scores[idx];
        if (mask[idx] == 0) v = -100000.0f;
        x[j] = v;
        m = fmaxf(m, v);
    }
    #pragma unroll
    for (int off = 32; off >= 1; off >>= 1)
        m = fmaxf(m, __shfl_xor(m, off, 64));
    if (lane == 0) sred[wid] = m;
    __syncthreads();
    m = fmaxf(fmaxf(sred[0], sred[1]), fmaxf(sred[2], sred[3]));

    float s = 0.0f;
    #pragma unroll
    for (int j = 0; j < 8; ++j) {
        float e = __expf(x[j] - m);
        x[j] = e;
        s += e;
    }
    #pragma unroll
    for (int off = 32; off >= 1; off >>= 1)
        s += __shfl_xor(s, off, 64);
    if (lane == 0) sred[4 + wid] = s;
    __syncthreads();
    s = sred[4] + sred[5] + sred[6] + sred[7];

    const float inv = 1.0f / s;
    #pragma unroll
    for (int j = 0; j < 8; ++j)
        out[b * Sdim + j * 256 + t] = x[j] * inv;
}

// ---------------- launch ----------------------------------------------------
extern "C" void kernel_launch(void* const* d_in, const int* in_sizes, int n_in,
                              void* d_out, int out_size, void* d_ws, size_t ws_size,
                              hipStream_t stream) {
    const float* dec  = (const float*)d_in[0];   // (B, H)
    const float* enc  = (const float*)d_in[1];   // (B, S, 2H)
    const int*   mask = (const int*)  d_in[2];   // (B, S)
    const float* W    = (const float*)d_in[3];   // (3H, H)
    const float* ba   = (const float*)d_in[4];   // (H,)
    const float* vw   = (const float*)d_in[5];   // (H,)
    float* out = (float*)d_out;                  // (B, S)

    // workspace layout (~1.3 MB)
    float* dec_proj = (float*)d_ws;                       // 32*512 f   = 64 KB
    short* Wbp      = (short*)(dec_proj + Bdim * Hdim);   // 512*1024 s = 1 MB (packed)
    float* scores   = (float*)(Wbp + Hdim * Kdim);        // 65536 f    = 256 KB

    prep_kernel<<<640, 256, 0, stream>>>(W, dec, ba, Wbp, dec_proj);
    scores_kernel<<<Mtot / BM, 512, 0, stream>>>(enc, Wbp, dec_proj, vw, scores);
    softmax_kernel<<<Bdim, 256, 0, stream>>>(scores, mask, out);
}